// Round 17
// baseline (74.481 us; speedup 1.0000x reference)
//
#include <hip/hip_runtime.h>
#include <math.h>

typedef float v2 __attribute__((ext_vector_type(2)));

#define SCALE 1073741824.0   // 2^30 fixed-point for deterministic atomic sum
#define NPIX 12582912.0      // 16*3*512*512
#define C1f 1e-4f
#define C2f 9e-4f

struct Wts {
    float w[11];   // V-pass weights
    v2 hp[12];     // H-pass pair weights for element j: (w[j]|0, w[j-1]|0)
};

__device__ __forceinline__ v2 sp(float x) { v2 r; r.x = x; r.y = x; return r; }
__device__ __forceinline__ v2 f2(v2 a, v2 b, v2 c) {
    return __builtin_elementwise_fma(a, b, c);
}

// SSIM tail for one output (step index tt): consumes 4 accumulators, adds to loc
#define SSIMTAIL(S_, D_, P_, M_, tt) do {                                   \
    const v2 ss_ = (S_) * (S_), dd_ = (D_) * (D_);                          \
    const v2 mu12_  = (ss_ - dd_) * sp(0.25f);                              \
    const v2 musq_  = (ss_ + dd_) * sp(0.5f);                               \
    const v2 sig12_ = ((P_) - (M_)) * sp(0.25f) - mu12_;                    \
    const v2 sigsm_ = ((P_) + (M_)) * sp(0.5f) - musq_;                     \
    const v2 num_ = (sp(2.f)*mu12_ + sp(C1f)) * (sp(2.f)*sig12_ + sp(C2f)); \
    const v2 den_ = (musq_ + sp(C1f)) * (sigsm_ + sp(C2f));                 \
    v2 r_;                                                                  \
    r_.x = __builtin_amdgcn_rcpf(den_.x);                                   \
    r_.y = __builtin_amdgcn_rcpf(den_.y);                                   \
    r_ = r_ * (sp(2.f) - den_ * r_);                                        \
    const float vm_ = ((tt) >= 11 && (r0 + (tt) - 11) < 512) ? 1.f : 0.f;   \
    loc = f2(num_ * sp(vm_), r_, loc);                                      \
} while (0)

// Full V-blur of phase PH (ring slots (PH+1..PH+11)%12) + tail
#define VOUTFULL(PH, tt) do {                                               \
    v2 S0 = sp(0.f), D0 = sp(0.f), P0 = sp(0.f), M0 = sp(0.f);              \
    _Pragma("unroll") for (int k = 0; k < 11; ++k) {                        \
        const int q = ((PH) + 1 + k) % 12;                                  \
        const v2 wk = sp(W.w[k]);                                           \
        S0 = f2(wk, rS[q], S0); D0 = f2(wk, rD[q], D0);                     \
        P0 = f2(wk, rP[q], P0); M0 = f2(wk, rM[q], M0);                     \
    }                                                                       \
    SSIMTAIL(S0, D0, P0, M0, tt);                                           \
} while (0)

// H-blur of row grow (chunks A,B) into ring slot PH, masked
#define HPUSH(PH, A, B, grow) do {                                          \
    v2 hS = sp(0.f), hD = sp(0.f), hP = sp(0.f), hM = sp(0.f);              \
    _Pragma("unroll") for (int j = 0; j < 12; ++j) {                        \
        const int e = j + 1;               /* element col = c - 6 + e */    \
        const float xa = (e & 1) ? A[e >> 1].y : A[e >> 1].x;               \
        const float xb = (e & 1) ? B[e >> 1].y : B[e >> 1].x;               \
        const float u = xa + xb, v = xa - xb;                               \
        hS = f2(hpl[j], sp(u), hS);                                         \
        hD = f2(hpl[j], sp(v), hD);                                         \
        hP = f2(hpl[j], sp(u * u), hP);                                     \
        hM = f2(hpl[j], sp(v * v), hM);                                     \
    }                                                                       \
    const float m = ((unsigned)(grow) < 512u) ? 1.f : 0.f;                  \
    const v2 mm = sp(m);                                                    \
    rS[PH] = hS * mm; rD[PH] = hD * mm;                                     \
    rP[PH] = hP * mm; rM[PH] = hM * mm;                                     \
} while (0)

// One PAIR = steps (ta, ta+1), ring phases (PA, PB)=(2J, 2J+1), ta=12*it+2J.
// Order: 28 loads -> VOUT(ta) -> partial VOUT(ta+1) over 10 old slots ->
// HP(ta) [vmcnt(14), covered] -> finish VOUT(ta+1) (k=10 = slot PA) ->
// HP(ta+1) [vmcnt(0), covered].
#define PAIR(J, PA, PB) do {                                                \
    const int ta = 12 * it + 2 * (J);                                       \
    const int ga = r0 - 5 + ta;                                             \
    const int gb = ga + 1;                                                  \
    const int rca = ga < 0 ? 0 : (ga > 511 ? 511 : ga);                     \
    const int rcb = gb < 0 ? 0 : (gb > 511 ? 511 : gb);                     \
    const float* raa = baseA + rca * 512;                                   \
    const float* rba = baseB + rca * 512;                                   \
    const float* rab = baseA + rcb * 512;                                   \
    const float* rbb = baseB + rcb * 512;                                   \
    _Pragma("unroll") for (int k = 0; k < 7; ++k) {                         \
        a0[k] = *(const v2*)(raa + off[k]);                                 \
        b0[k] = *(const v2*)(rba + off[k]);                                 \
    }                                                                       \
    _Pragma("unroll") for (int k = 0; k < 7; ++k) {                         \
        a1[k] = *(const v2*)(rab + off[k]);                                 \
        b1[k] = *(const v2*)(rbb + off[k]);                                 \
    }                                                                       \
    VOUTFULL(PA, ta);                                                       \
    v2 S1 = sp(0.f), D1 = sp(0.f), P1 = sp(0.f), M1 = sp(0.f);              \
    _Pragma("unroll") for (int k = 0; k < 10; ++k) {                        \
        const int q = ((PB) + 1 + k) % 12;   /* old slots only */           \
        const v2 wk = sp(W.w[k]);                                           \
        S1 = f2(wk, rS[q], S1); D1 = f2(wk, rD[q], D1);                     \
        P1 = f2(wk, rP[q], P1); M1 = f2(wk, rM[q], M1);                     \
    }                                                                       \
    HPUSH(PA, a0, b0, ga);                                                  \
    {                                                                       \
        const v2 w10 = sp(W.w[10]);          /* k=10 tap: slot PA (row ta)*/\
        S1 = f2(w10, rS[PA], S1); D1 = f2(w10, rD[PA], D1);                 \
        P1 = f2(w10, rP[PA], P1); M1 = f2(w10, rM[PA], M1);                 \
        SSIMTAIL(S1, D1, P1, M1, ta + 1);                                   \
    }                                                                       \
    HPUSH(PB, a1, b1, gb);                                                  \
    __builtin_amdgcn_sched_barrier(0);       /* bound live ranges per pair*/\
} while (0)

__global__ __launch_bounds__(256, 2) void ssim_main(
    const float* __restrict__ img1, const float* __restrict__ img2,
    unsigned long long* __restrict__ acc, Wts W)
{
    __shared__ float red[4];
    const int tid = threadIdx.x;
    const int lane = tid & 63;
    const int wv = tid >> 6;
    const int r0 = blockIdx.x * 37;            // 14 strips of 37 output rows
    const int plane = blockIdx.y;              // 48 planes
    const int c = wv * 128 + 2 * lane;         // this thread's columns c, c+1

    const float* baseA = img1 + (size_t)plane * 262144;
    const float* baseB = img2 + (size_t)plane * 262144;

    // per-lane clamped chunk offsets (7 x float2 chunks covering [c-6, c+8))
    int off[7];
#pragma unroll
    for (int k = 0; k < 7; ++k) {
        int o = c - 6 + 2 * k;
        off[k] = o < 0 ? 0 : (o > 510 ? 510 : o);
    }
    // per-lane H weight pairs, zeroed where the element column is out of image
    v2 hpl[12];
#pragma unroll
    for (int j = 0; j < 12; ++j) {
        const int col = c - 5 + j;
        hpl[j] = (col >= 0 && col < 512) ? W.hp[j] : sp(0.f);
    }

    v2 rS[12], rD[12], rP[12], rM[12];         // 12-slot ring (dead-slot VOUT)
#pragma unroll
    for (int q = 0; q < 12; ++q) {             // zero ring: prologue VOUTs stay
        rS[q] = sp(0.f); rD[q] = sp(0.f);      // finite (den=C1*C2>0), masked
        rP[q] = sp(0.f); rM[q] = sp(0.f);
    }
    v2 a0[7], b0[7], a1[7], b1[7];             // two rows' chunks (ILP)
    v2 loc = sp(0.f);

    // ---- 48 steps = 4 x (6-pair body); all ring indices literal ----------
    for (int it = 0; it < 4; ++it) {
        PAIR(0, 0, 1);  PAIR(1, 2, 3);  PAIR(2, 4, 5);
        PAIR(3, 6, 7);  PAIR(4, 8, 9);  PAIR(5, 10, 11);
    }

    // ---- reduction -> fixed-point global atomic ----
    float l = loc.x + loc.y;
#pragma unroll
    for (int o2 = 32; o2; o2 >>= 1)
        l += __shfl_down(l, o2, 64);
    if (lane == 0) red[wv] = l;
    __syncthreads();
    if (tid == 0) {
        const float bs = red[0] + red[1] + red[2] + red[3];
        const unsigned long long q =
            (unsigned long long)__double2ll_rn((double)bs * SCALE);
        atomicAdd(acc, q);
    }
}

__global__ void ssim_final(const unsigned long long* __restrict__ acc,
                           float* __restrict__ out)
{
    if (threadIdx.x == 0)
        out[0] = (float)((double)(*acc) * (1.0 / SCALE) / NPIX);
}

extern "C" void kernel_launch(void* const* d_in, const int* in_sizes, int n_in,
                              void* d_out, int out_size, void* d_ws, size_t ws_size,
                              hipStream_t stream) {
    const float* img1 = (const float*)d_in[0];
    const float* img2 = (const float*)d_in[1];
    float* out = (float*)d_out;
    unsigned long long* acc = (unsigned long long*)d_ws;

    double g[11], ssum = 0.0;
    for (int i = 0; i < 11; ++i) {
        const double d = (double)(i - 5);
        g[i] = exp(-(d * d) / 4.5);
        ssum += g[i];
    }
    Wts W;
    for (int i = 0; i < 11; ++i) W.w[i] = (float)(g[i] / ssum);
    for (int j = 0; j < 12; ++j) {
        v2 p;
        p.x = (j <= 10) ? W.w[j] : 0.f;      // out0 weight for window col c-5+j
        p.y = (j >= 1) ? W.w[j - 1] : 0.f;   // out1 weight
        W.hp[j] = p;
    }

    hipMemsetAsync(d_ws, 0, sizeof(unsigned long long), stream);
    ssim_main<<<dim3(14, 48), 256, 0, stream>>>(img1, img2, acc, W);
    ssim_final<<<1, 64, 0, stream>>>(acc, out);
}